// Round 5
// baseline (24.375 us; speedup 1.0000x reference)
//
#include <hip/hip_runtime.h>

// SpanRepresentation: B=16, L=128, D=768, W=128, SPAN_MAX_LEN=8 -> n_spans=996
// out = spans (B,996,1664) f32 ++ span_indices (996,2) as float, flat.
//
// R2: XCD-partitioned (blockIdx%8 -> 2-batch slab, reads stay XCD-L2-local).
// R3: plain stores (nt was neutral-to-worse).
// R4: 4 independent load->store pairs per thread (MLP x4, 4x fewer waves,
//     16KB sequential output per block).

#define LSEQ    128
#define DDIM    768
#define WDIM    128
#define NSPANS  996
#define ROW     1664            // 2*D + W
#define ROW4    416             // ROW/4
#define PER_B4  (NSPANS * ROW4) // 414336 float4s per batch
#define SLAB4   (2 * PER_B4)    // 828672 float4s per XCD (2 batches)
#define JJ_PER_XCD 810          // ceil(SLAB4 / (4*256))
#define NWG_MAIN (8 * JJ_PER_XCD)
#define IDX4    498             // (996*2)/4 float4s of index tail

typedef float f4 __attribute__((ext_vector_type(4)));

__device__ __forceinline__ void decode_span(int s, int& start, int& end, int& bucket) {
    int w = 1, base = 0;
    if (s >= 128) { w = 2; base = 128; }
    if (s >= 255) { w = 3; base = 255; }
    if (s >= 381) { w = 4; base = 381; }
    if (s >= 506) { w = 5; base = 506; }
    if (s >= 630) { w = 6; base = 630; }
    if (s >= 753) { w = 7; base = 753; }
    if (s >= 875) { w = 8; base = 875; }
    start  = s - base;
    end    = start + w - 1;
    bucket = w - (w >= 6 ? 1 : 0);   // widths 1..8 -> buckets 1,2,3,4,5,5,6,7
}

__global__ __launch_bounds__(256) void span_rep_kernel(
        const float* __restrict__ x,
        const float* __restrict__ we,
        float* __restrict__ out) {
    const int wg = blockIdx.x;

    if (wg < NWG_MAIN) {
        const int xcd = wg & 7;
        const int jj  = wg >> 3;
        const int b0  = 2 * xcd;
        const float* xb   = x   + (long)b0 * LSEQ * DDIM;
        float*       outb = out + (long)b0 * PER_B4 * 4;

        f4  v0, v1, v2, v3;
        int i0, i1, i2, i3;
        bool m0, m1, m2, m3;

        // ---- phase 1: issue 4 independent gathers ----
        #define LOADK(K, VK, IK, MK)                                          \
        {                                                                     \
            const int idx = (jj * 4 + K) * 256 + (int)threadIdx.x;            \
            MK = (idx < SLAB4);                                               \
            IK = idx;                                                         \
            if (MK) {                                                         \
                const int half = (idx >= PER_B4) ? 1 : 0;                     \
                const int rem  = idx - half * PER_B4;                         \
                const int s    = rem / ROW4;                                  \
                const int c    = (rem - s * ROW4) * 4;                        \
                int start, end, bucket;                                       \
                decode_span(s, start, end, bucket);                           \
                if (c < DDIM) {                                               \
                    VK = *reinterpret_cast<const f4*>(                        \
                        &xb[((long)half * LSEQ * DDIM) + (long)start * DDIM + c]); \
                } else if (c < 2 * DDIM) {                                    \
                    VK = *reinterpret_cast<const f4*>(                        \
                        &xb[((long)half * LSEQ * DDIM) + (long)end * DDIM + (c - DDIM)]); \
                } else {                                                      \
                    VK = *reinterpret_cast<const f4*>(                        \
                        &we[bucket * WDIM + (c - 2 * DDIM)]);                 \
                }                                                             \
            }                                                                 \
        }
        LOADK(0, v0, i0, m0)
        LOADK(1, v1, i1, m1)
        LOADK(2, v2, i2, m2)
        LOADK(3, v3, i3, m3)
        #undef LOADK

        // ---- phase 2: 4 independent stores ----
        if (m0) *reinterpret_cast<f4*>(&outb[(long)i0 * 4]) = v0;
        if (m1) *reinterpret_cast<f4*>(&outb[(long)i1 * 4]) = v1;
        if (m2) *reinterpret_cast<f4*>(&outb[(long)i2 * 4]) = v2;
        if (m3) *reinterpret_cast<f4*>(&outb[(long)i3 * 4]) = v3;
    } else {
        const int k = (wg - NWG_MAIN) * 256 + threadIdx.x;  // tail float4 index
        if (k < IDX4) {
            int s0 = 2 * k, s1 = 2 * k + 1;
            int st0, en0, bk0, st1, en1, bk1;
            decode_span(s0, st0, en0, bk0);
            decode_span(s1, st1, en1, bk1);
            f4 v = { (float)st0, (float)en0, (float)st1, (float)en1 };
            *reinterpret_cast<f4*>(&out[(long)16 * PER_B4 * 4 + (long)k * 4]) = v;
        }
    }
}

extern "C" void kernel_launch(void* const* d_in, const int* in_sizes, int n_in,
                              void* d_out, int out_size, void* d_ws, size_t ws_size,
                              hipStream_t stream) {
    const float* x  = (const float*)d_in[0];
    const float* we = (const float*)d_in[1];
    float* out = (float*)d_out;

    const int grid = NWG_MAIN + 2;   // +2 blocks cover the 498-float4 index tail
    span_rep_kernel<<<grid, 256, 0, stream>>>(x, we, out);
}

// Round 6
// 22.172 us; speedup vs baseline: 1.0994x; 1.0994x over previous
//
#include <hip/hip_runtime.h>

// SpanRepresentation: B=16, L=128, D=768, W=128, SPAN_MAX_LEN=8 -> n_spans=996
// out = spans (B,996,1664) f32 ++ span_indices (996,2) as float, flat.
//
// R5: source-centric scatter. Width-major span enumeration means group w's
// hi-part is x[b,0:129-w,:] and hj-part is x[b,w-1:128,:] (contiguous!).
// One x float4 load -> up to 16 stores (hi+hj for w=1..8), wave-uniform
// masks, zero per-element decode. Reads drop 16x (106MB -> 6.6MB).

#define LSEQ   128
#define DDIM   768
#define NSPANS 996
#define ROW    1664
#define PER_B  ((long)NSPANS * ROW)      // floats per batch in spans
#define XPART_BLOCKS 1536                // 16 b * 128 s * 3 q waves / 4 waves-per-block
#define FW_BLOCKS    1992                // 16*996*32 float4s / 256
#define FWTOT        509952              // 16*996*32
#define IDX4         498
#define SPANS_FLOATS ((long)16 * PER_B)  // start of index tail

typedef float f4 __attribute__((ext_vector_type(4)));

// group base rows (compile-time): widths 1..8
__device__ __constant__ int kBase[8] = {0, 128, 255, 381, 506, 630, 753, 875};

__device__ __forceinline__ int bucket_of_span(int s) {
    // width-major: bucket = w - (w>=6), w from compare chain
    int w = 1;
    if (s >= 128) w = 2;
    if (s >= 255) w = 3;
    if (s >= 381) w = 4;
    if (s >= 506) w = 5;
    if (s >= 630) w = 6;
    if (s >= 753) w = 7;
    if (s >= 875) w = 8;
    return w - (w >= 6 ? 1 : 0);
}

__device__ __forceinline__ void start_end_of_span(int s, int& start, int& end) {
    int w = 1, base = 0;
    if (s >= 128) { w = 2; base = 128; }
    if (s >= 255) { w = 3; base = 255; }
    if (s >= 381) { w = 4; base = 381; }
    if (s >= 506) { w = 5; base = 506; }
    if (s >= 630) { w = 6; base = 630; }
    if (s >= 753) { w = 7; base = 753; }
    if (s >= 875) { w = 8; base = 875; }
    start = s - base;
    end   = start + w - 1;
}

__global__ __launch_bounds__(256) void span_rep_kernel(
        const float* __restrict__ x,
        const float* __restrict__ we,
        float* __restrict__ out) {
    const int wg = blockIdx.x;

    if (wg < XPART_BLOCKS) {
        // ---- x-part: one load -> 16 scatter-stores ----
        const int xcd  = wg & 7;          // XCD slab: batches {2*xcd, 2*xcd+1}
        const int jj   = wg >> 3;         // [0,192)
        const int wave = threadIdx.x >> 6;
        const int lane = threadIdx.x & 63;
        const int gw   = jj * 4 + wave;   // [0,768) waves per XCD slab
        const int half = (gw >= 384) ? 1 : 0;
        const int b    = 2 * xcd + half;
        const int r    = gw - half * 384; // [0,384)
        const int s    = r / 3;           // source row, wave-uniform
        const int q    = r - s * 3;       // which 64-f4 chunk of the 192-f4 row
        const int c    = (q * 64 + lane) * 4;   // [0,768) float col

        const f4 v = *reinterpret_cast<const f4*>(
            &x[((long)b * LSEQ + s) * DDIM + c]);

        float* ob = out + (long)b * PER_B;   // this batch's span block

        #pragma unroll
        for (int w = 1; w <= 8; ++w) {
            const int base = (w==1)?0:(w==2)?128:(w==3)?255:(w==4)?381:
                             (w==5)?506:(w==6)?630:(w==7)?753:875;
            if (s <= LSEQ - w) {          // hi of span row base+s (wave-uniform)
                *reinterpret_cast<f4*>(&ob[(long)(base + s) * ROW + c]) = v;
            }
            if (s >= w - 1) {             // hj of span row base+s-w+1
                *reinterpret_cast<f4*>(&ob[(long)(base + s - w + 1) * ROW + DDIM + c]) = v;
            }
        }
    } else if (wg < XPART_BLOCKS + FW_BLOCKS) {
        // ---- fw-part: width-embedding broadcast, (b, span, 32 f4) ----
        const int f = (wg - XPART_BLOCKS) * 256 + (int)threadIdx.x;  // [0, FWTOT)
        const int b    = f / 31872;           // 996*32
        const int rem  = f - b * 31872;
        const int sIdx = rem >> 5;            // span row
        const int c4f  = rem & 31;            // f4 within fw segment
        const int bucket = bucket_of_span(sIdx);
        const f4 v = *reinterpret_cast<const f4*>(&we[bucket * 128 + c4f * 4]);
        *reinterpret_cast<f4*>(
            &out[(long)b * PER_B + (long)sIdx * ROW + 2 * DDIM + c4f * 4]) = v;
    } else {
        // ---- index tail ----
        const int k = (wg - XPART_BLOCKS - FW_BLOCKS) * 256 + (int)threadIdx.x;
        if (k < IDX4) {
            int st0, en0, st1, en1;
            start_end_of_span(2 * k,     st0, en0);
            start_end_of_span(2 * k + 1, st1, en1);
            f4 v = { (float)st0, (float)en0, (float)st1, (float)en1 };
            *reinterpret_cast<f4*>(&out[SPANS_FLOATS + (long)k * 4]) = v;
        }
    }
}

extern "C" void kernel_launch(void* const* d_in, const int* in_sizes, int n_in,
                              void* d_out, int out_size, void* d_ws, size_t ws_size,
                              hipStream_t stream) {
    const float* x  = (const float*)d_in[0];
    const float* we = (const float*)d_in[1];
    float* out = (float*)d_out;

    const int grid = XPART_BLOCKS + FW_BLOCKS + 2;
    span_rep_kernel<<<grid, 256, 0, stream>>>(x, we, out);
}